// Round 11
// baseline (257.737 us; speedup 1.0000x reference)
//
#include <hip/hip_runtime.h>
#include <hip/hip_bf16.h>
#include <math.h>

#define M_HALF 2097152          // 2^21, half-length complex IFFT size
#define M64    32768            // M_HALF / 64

typedef __bf16 bf16_t;
typedef __attribute__((ext_vector_type(8))) __bf16 bf8;
typedef __attribute__((ext_vector_type(4))) __bf16 bf4;
typedef __attribute__((ext_vector_type(4))) float f32x4;

#define GLOBAL_AS __attribute__((address_space(1)))
#define LDS_AS    __attribute__((address_space(3)))

__device__ __forceinline__ float2 cadd(float2 a, float2 b){ return make_float2(a.x+b.x, a.y+b.y); }
__device__ __forceinline__ float2 csub(float2 a, float2 b){ return make_float2(a.x-b.x, a.y-b.y); }
__device__ __forceinline__ float2 cmul(float2 a, float2 b){ return make_float2(a.x*b.x-a.y*b.y, a.x*b.y+a.y*b.x); }
__device__ __forceinline__ float2 cmuli(float2 a){ return make_float2(-a.y, a.x); } // *(+i)

// inverse 8-point DFT (positive exponent), natural order
__device__ __forceinline__ void radix8_inv(const float2 v[8], float2 X[8]) {
    const float cc = 0.70710678118654752f;
    float2 a0 = cadd(v[0], v[4]), a1 = cadd(v[1], v[5]), a2 = cadd(v[2], v[6]), a3 = cadd(v[3], v[7]);
    float2 b0 = csub(v[0], v[4]), b1 = csub(v[1], v[5]), b2 = csub(v[2], v[6]), b3 = csub(v[3], v[7]);
    b1 = cmul(b1, make_float2(cc, cc));
    b2 = cmuli(b2);
    b3 = cmul(b3, make_float2(-cc, cc));
    float2 c0 = cadd(a0, a2), c1 = cadd(a1, a3), d0 = csub(a0, a2), d1 = cmuli(csub(a1, a3));
    float2 e0 = cadd(b0, b2), e1 = cadd(b1, b3), f0 = csub(b0, b2), f1 = cmuli(csub(b1, b3));
    X[0] = cadd(c0, c1); X[4] = csub(c0, c1); X[2] = cadd(d0, d1); X[6] = csub(d0, d1);
    X[1] = cadd(e0, e1); X[5] = csub(e0, e1); X[3] = cadd(f0, f1); X[7] = csub(f0, f1);
}

// ---------------- zero / scatter ----------------

__global__ __launch_bounds__(256) void zero2_kernel(float2* p, int n) {
    int i = blockIdx.x*256 + threadIdx.x;
    if (i < n) p[i] = make_float2(0.f, 0.f);
}

__global__ __launch_bounds__(256) void scatter_kernel(const float* __restrict__ cr,
                                                      const float* __restrict__ ci,
                                                      const int* __restrict__ idx,
                                                      float2* __restrict__ spec, int keep) {
    int i = blockIdx.x*256 + threadIdx.x;
    if (i < keep) {
        int k = idx[i];
        spec[k] = make_float2(cr[i], ci[i]);
    }
}

// ---------------- first pass: radix-512 in-block (8^3), prep fused, NS=1 ----
__global__ __launch_bounds__(512) void ifft_pass512_first(const float2* __restrict__ spec,
                                                          float2* __restrict__ dst,
                                                          const float* __restrict__ scale) {
    __shared__ float2 ex[8 * 642];
    const int tid = threadIdx.x;
    const int jl = tid & 7, x = tid >> 3;
    const int j = blockIdx.x * 8 + jl;
    float2* W = ex + jl * 642;

    float2 v[8];
    const float s = scale[0] * (1.0f/(float)M_HALF);
#pragma unroll
    for (int u = 0; u < 8; ++u) {
        int k = j + (x + 64*u) * 4096;
        float2 a = spec[k];
        float2 b = spec[M_HALF - k];
        if (k == 0) { a.y = 0.0f; b.y = 0.0f; }
        float Er = 0.5f*(a.x + b.x), Ei = 0.5f*(a.y - b.y);
        float Tr = 0.5f*(a.x - b.x), Ti = 0.5f*(a.y + b.y);
        float ang = (float)(3.14159265358979323846 * (double)k / (double)M_HALF);
        float sn, cs; sincosf(ang, &sn, &cs);
        float Or = Tr*cs - Ti*sn, Oi = Tr*sn + Ti*cs;
        v[u] = make_float2((Er - Oi)*s, (Ei + Or)*s);
    }
    float2 E[8];
    radix8_inv(v, E);
    {   // T1 = cis(2pi s8 x / 512)
        float cb, sb; sincosf((float)x * 0.012271846303085130f, &sb, &cb);
        float2 wb = make_float2(cb, sb), w = make_float2(1.f, 0.f);
#pragma unroll
        for (int s8 = 0; s8 < 8; ++s8) {
            W[s8*65 + x] = cmul(E[s8], w);
            w = cmul(w, wb);
        }
    }
    __syncthreads();
    const int p = x >> 3, xa = x & 7;
    float2 g[8];
#pragma unroll
    for (int xb = 0; xb < 8; ++xb) g[xb] = W[p*65 + xa + 8*xb];
    float2 H[8];
    radix8_inv(g, H);
    __syncthreads();
    {   // T2 = cis(2pi o8 xa / 64)
        float cb, sb; sincosf((float)xa * 0.098174770424681039f, &sb, &cb);
        float2 wb = make_float2(cb, sb), w = make_float2(1.f, 0.f);
#pragma unroll
        for (int o8 = 0; o8 < 8; ++o8) {
            W[p*81 + o8*9 + xa] = cmul(H[o8], w);
            w = cmul(w, wb);
        }
    }
    __syncthreads();
    const int pp = x & 7, sp = x >> 3;
    float2 r[8];
#pragma unroll
    for (int xa2 = 0; xa2 < 8; ++xa2) r[xa2] = W[pp*81 + sp*9 + xa2];
    float2 D[8];
    radix8_inv(r, D);
    const long base = (long)j * 512;
#pragma unroll
    for (int ob = 0; ob < 8; ++ob)
        dst[base + x + 64*ob] = D[ob];
}

// ---------------- radix-64 Stockham middle pass (two radix-8 + LDS) ----------
template<int NS>
__global__ __launch_bounds__(256) void ifft_pass64(const float2* __restrict__ src,
                                                   float2* __restrict__ dst) {
    __shared__ float2 ex[32][65];
    const int tid = threadIdx.x;
    const int x = tid >> 5, gl = tid & 31;
    const int jg = blockIdx.x * 32 + gl;
    const int jm = jg & (NS - 1);
    float2 v[8];
#pragma unroll
    for (int u = 0; u < 8; ++u)
        v[u] = src[jg + (x + 8*u) * M64];
    {
        double th = 6.283185307179586 * (double)jm / (double)(NS * 64);
        float c0, s0, c8, s8;
        sincosf((float)(th * (double)x), &s0, &c0);
        sincosf((float)(th * 8.0), &s8, &c8);
        float2 w = make_float2(c0, s0), w8 = make_float2(c8, s8);
#pragma unroll
        for (int u = 0; u < 8; ++u) {
            v[u] = cmul(v[u], w);
            w = cmul(w, w8);
        }
    }
    float2 X[8];
    radix8_inv(v, X);
    {
        float cb, sb; sincosf((float)x * 0.09817477042468103f, &sb, &cb);
        float2 wb = make_float2(cb, sb), wc = make_float2(1.f, 0.f);
#pragma unroll
        for (int s2 = 0; s2 < 8; ++s2) {
            ex[gl][x*8 + s2] = cmul(X[s2], wc);
            wc = cmul(wc, wb);
        }
    }
    __syncthreads();
    float2 W2[8];
#pragma unroll
    for (int t1 = 0; t1 < 8; ++t1) W2[t1] = ex[gl][t1*8 + x];
    float2 Y[8];
    radix8_inv(W2, Y);
    const long obase = (long)(jg - jm) * 64 + jm;
#pragma unroll
    for (int s1 = 0; s1 < 8; ++s1)
        dst[obase + (long)(x + 8*s1) * NS] = Y[s1];
}

// ---------------- radix-64 FINAL pass, packed-bf16 output ----------------
template<int NS>
__global__ __launch_bounds__(256) void ifft_pass64_bf(const float2* __restrict__ src,
                                                      bf16_t* __restrict__ dstw) {
    __shared__ float2 ex[32][65];
    const int tid = threadIdx.x;
    const int x = tid >> 5, gl = tid & 31;
    const int jg = blockIdx.x * 32 + gl;
    const int jm = jg & (NS - 1);
    float2 v[8];
#pragma unroll
    for (int u = 0; u < 8; ++u)
        v[u] = src[jg + (x + 8*u) * M64];
    {
        double th = 6.283185307179586 * (double)jm / (double)(NS * 64);
        float c0, s0, c8, s8;
        sincosf((float)(th * (double)x), &s0, &c0);
        sincosf((float)(th * 8.0), &s8, &c8);
        float2 w = make_float2(c0, s0), w8 = make_float2(c8, s8);
#pragma unroll
        for (int u = 0; u < 8; ++u) {
            v[u] = cmul(v[u], w);
            w = cmul(w, w8);
        }
    }
    float2 X[8];
    radix8_inv(v, X);
    {
        float cb, sb; sincosf((float)x * 0.09817477042468103f, &sb, &cb);
        float2 wb = make_float2(cb, sb), wc = make_float2(1.f, 0.f);
#pragma unroll
        for (int s2 = 0; s2 < 8; ++s2) {
            ex[gl][x*8 + s2] = cmul(X[s2], wc);
            wc = cmul(wc, wb);
        }
    }
    __syncthreads();
    float2 W2[8];
#pragma unroll
    for (int t1 = 0; t1 < 8; ++t1) W2[t1] = ex[gl][t1*8 + x];
    float2 Y[8];
    radix8_inv(W2, Y);
    const long obase = (long)(jg - jm) * 64 + jm;
#pragma unroll
    for (int s1 = 0; s1 < 8; ++s1) {
        long n = obase + (long)(x + 8*s1) * NS;
        bf16_t lo = (bf16_t)Y[s1].x, hi = (bf16_t)Y[s1].y;
        unsigned int pk = ((unsigned int)*(unsigned short*)&hi << 16) |
                           (unsigned int)*(unsigned short*)&lo;
        ((unsigned int*)dstw)[n] = pk;
    }
}

// ---------------- transpose bf16 (w[R][C] -> wT[C][R]) ----------------

__global__ __launch_bounds__(256) void transpose_bf_kernel(const bf16_t* __restrict__ w,
                                                           bf16_t* __restrict__ wT,
                                                           int R, int C) {
    __shared__ bf16_t tile[32][33];
    int tx = threadIdx.x & 31, ty = threadIdx.x >> 5;
    long c0 = (long)blockIdx.x * 32, r0 = (long)blockIdx.y * 32;
#pragma unroll
    for (int i = 0; i < 4; ++i)
        tile[ty + i*8][tx] = w[(r0 + ty + i*8) * C + c0 + tx];
    __syncthreads();
#pragma unroll
    for (int i = 0; i < 4; ++i) {
        int c = ty + i*8;
        wT[(c0 + c) * R + r0 + tx] = tile[tx][c];
    }
}

// ---------------- fp32 -> bf16 convert (x) ----------------

__global__ __launch_bounds__(256) void cvt_bf16_kernel(const float* __restrict__ in,
                                                       bf16_t* __restrict__ out, int n4) {
    int i = blockIdx.x*256 + threadIdx.x;
    if (i < n4) {
        float4 v = ((const float4*)in)[i];
        bf4 o;
        o[0] = (bf16_t)v.x; o[1] = (bf16_t)v.y; o[2] = (bf16_t)v.z; o[3] = (bf16_t)v.w;
        ((bf4*)out)[i] = o;
    }
}

// ---------------- shared staging helper (swizzled, N 1KiB-chunks/wave) -------
// LDS[row][cb] = G[row][cb ^ ((row&7)<<4)] (16B granules): pre-swizzled global
// source -> linear global_load_lds dest; reads apply the same XOR (0 conflicts).

template<int NITER>
__device__ __forceinline__ void stage_sw(const bf16_t* g, int ld, int row0, int col0,
                                         bf16_t* lds, int tid) {
    int w = tid >> 6, l = tid & 63;        // w in [0,8)
    int r8 = l >> 3;
    int cg = ((l & 7) ^ r8) << 3;
#pragma unroll
    for (int i = 0; i < NITER; ++i) {
        int chunk = (i << 3) + w;          // NITER*8 chunks x 8 rows x 64 cols
        const bf16_t* ga = g + (long)(row0 + chunk*8 + r8) * ld + col0 + cg;
        bf16_t* la = lds + (chunk << 9);
        __builtin_amdgcn_global_load_lds((const GLOBAL_AS unsigned int*)ga,
                                         (LDS_AS unsigned int*)la, 16, 0, 0);
    }
}

// ---------------- 128x128-tile GEMM, 8 waves (GEMM2) ----------------

template<int EPI>  // 0: bias+gelu -> bf16 ; 1: bias -> fp32
__global__ __launch_bounds__(512, 6) void gemm_bt8(const bf16_t* __restrict__ A,
                                                   const bf16_t* __restrict__ Bt,
                                                   const float* __restrict__ bias,
                                                   void* __restrict__ Cout,
                                                   int M, int N, int K,
                                                   int CR, int CC, int GXC) {
    __shared__ __align__(16) bf16_t lA[128*64];
    __shared__ __align__(16) bf16_t lB[128*64];
    const int tid = threadIdx.x;
    const int l = tid & 63, w = tid >> 6;
    const int wr = w >> 2, wc = w & 3;
    int flat = blockIdx.y * gridDim.x + blockIdx.x;
    int r = flat & 7, q = flat >> 3;
    int ty = (r / GXC) * CR + q / CC;
    int tx = (r % GXC) * CC + q % CC;
    const int row0 = ty * 128, col0 = tx * 128;
    const int lr = l & 15, lq = l >> 4;
    const int xr = (lr & 7) << 4;
    f32x4 acc[4][2] = {};
    for (int k0 = 0; k0 < K; k0 += 64) {
        stage_sw<2>(A,  K, row0, k0, lA, tid);
        stage_sw<2>(Bt, K, col0, k0, lB, tid);
        __syncthreads();
#pragma unroll
        for (int kk = 0; kk < 2; ++kk) {
            bf8 af[4], bfr[2];
            const int kb = ((kk << 6) + lq*16) ^ xr;
#pragma unroll
            for (int mi = 0; mi < 4; ++mi)
                af[mi] = *(const bf8*)((const char*)lA + (wr*64 + mi*16 + lr)*128 + kb);
#pragma unroll
            for (int ni = 0; ni < 2; ++ni)
                bfr[ni] = *(const bf8*)((const char*)lB + (wc*32 + ni*16 + lr)*128 + kb);
#pragma unroll
            for (int mi = 0; mi < 4; ++mi)
#pragma unroll
                for (int ni = 0; ni < 2; ++ni)
                    acc[mi][ni] = __builtin_amdgcn_mfma_f32_16x16x32_bf16(
                        af[mi], bfr[ni], acc[mi][ni], 0, 0, 0);
        }
        __syncthreads();
    }
#pragma unroll
    for (int mi = 0; mi < 4; ++mi) {
#pragma unroll
        for (int ni = 0; ni < 2; ++ni) {
            int c = col0 + wc*32 + ni*16 + lr;
            float bv = bias[c];
#pragma unroll
            for (int q2 = 0; q2 < 4; ++q2) {
                int rr = row0 + wr*64 + mi*16 + lq*4 + q2;
                float v = acc[mi][ni][q2] + bv;
                if constexpr (EPI == 0) {
                    v = 0.5f * v * (1.0f + erff(v * 0.70710678118654752f));
                    ((bf16_t*)Cout)[(long)rr * N + c] = (bf16_t)v;
                } else {
                    ((float*)Cout)[(long)rr * N + c] = v;
                }
            }
        }
    }
}

// ---------------- 128x256-tile GEMM, 8 waves (GEMM1) ----------------
// Round-11: wider N-tile raises MFMA density: per K-step/thread 16 ds_read ->
// 32 MFMA (2.0 MFMA/read vs 1.33), staging bytes/MFMA -27%, A-fetch halves.
// acc 4x4 (64 AGPR) + operands ~48 -> needs ~115 regs: __launch_bounds__(512,4)
// keeps the 128-reg budget (no regalloc squeeze; (512,6)'s 85 would squeeze).
// 48 KiB LDS; 2 blocks/CU (GEMM2 proves 2/CU sustains ~916 TF at good density).

template<int EPI>
__global__ __launch_bounds__(512, 4) void gemm_bt8w(const bf16_t* __restrict__ A,
                                                    const bf16_t* __restrict__ Bt,
                                                    const float* __restrict__ bias,
                                                    void* __restrict__ Cout,
                                                    int M, int N, int K,
                                                    int CR, int CC, int GXC) {
    __shared__ __align__(16) bf16_t lA[128*64];
    __shared__ __align__(16) bf16_t lB[256*64];
    const int tid = threadIdx.x;
    const int l = tid & 63, w = tid >> 6;
    const int wr = w >> 2, wc = w & 3;           // 2M x 4N waves, 64x64 each
    int flat = blockIdx.y * gridDim.x + blockIdx.x;
    int r = flat & 7, q = flat >> 3;
    int ty = (r / GXC) * CR + q / CC;
    int tx = (r % GXC) * CC + q % CC;
    const int row0 = ty * 128, col0 = tx * 256;
    const int lr = l & 15, lq = l >> 4;
    const int xr = (lr & 7) << 4;
    f32x4 acc[4][4] = {};
    for (int k0 = 0; k0 < K; k0 += 64) {
        stage_sw<2>(A,  K, row0, k0, lA, tid);
        stage_sw<4>(Bt, K, col0, k0, lB, tid);
        __syncthreads();
#pragma unroll
        for (int kk = 0; kk < 2; ++kk) {
            bf8 af[4], bfr[4];
            const int kb = ((kk << 6) + lq*16) ^ xr;
#pragma unroll
            for (int mi = 0; mi < 4; ++mi)
                af[mi] = *(const bf8*)((const char*)lA + (wr*64 + mi*16 + lr)*128 + kb);
#pragma unroll
            for (int ni = 0; ni < 4; ++ni)
                bfr[ni] = *(const bf8*)((const char*)lB + (wc*64 + ni*16 + lr)*128 + kb);
#pragma unroll
            for (int mi = 0; mi < 4; ++mi)
#pragma unroll
                for (int ni = 0; ni < 4; ++ni)
                    acc[mi][ni] = __builtin_amdgcn_mfma_f32_16x16x32_bf16(
                        af[mi], bfr[ni], acc[mi][ni], 0, 0, 0);
        }
        __syncthreads();
    }
#pragma unroll
    for (int mi = 0; mi < 4; ++mi) {
#pragma unroll
        for (int ni = 0; ni < 4; ++ni) {
            int c = col0 + wc*64 + ni*16 + lr;
            float bv = bias[c];
#pragma unroll
            for (int q2 = 0; q2 < 4; ++q2) {
                int rr = row0 + wr*64 + mi*16 + lq*4 + q2;
                float v = acc[mi][ni][q2] + bv;
                if constexpr (EPI == 0) {
                    v = 0.5f * v * (1.0f + erff(v * 0.70710678118654752f));
                    ((bf16_t*)Cout)[(long)rr * N + c] = (bf16_t)v;
                } else {
                    ((float*)Cout)[(long)rr * N + c] = v;
                }
            }
        }
    }
}

// ---------------- launch ----------------

extern "C" void kernel_launch(void* const* d_in, const int* in_sizes, int n_in,
                              void* d_out, int out_size, void* d_ws, size_t ws_size,
                              hipStream_t stream) {
    const float* x        = (const float*)d_in[0];
    const float* fc_cr    = (const float*)d_in[1];
    const float* fc_ci    = (const float*)d_in[2];
    const int*   fc_idx   = (const int*)  d_in[3];
    const float* fc_scale = (const float*)d_in[4];
    const float* fc_bias  = (const float*)d_in[5];
    const float* pj_cr    = (const float*)d_in[6];
    const float* pj_ci    = (const float*)d_in[7];
    const int*   pj_idx   = (const int*)  d_in[8];
    const float* pj_scale = (const float*)d_in[9];
    const float* pj_bias  = (const float*)d_in[10];
    const int keep = in_sizes[1];

    char* ws = (char*)d_ws;
    bf16_t* w_fcT = (bf16_t*)(ws + 0);          //  8 MiB  [4096][1024]
    bf16_t* w_pjT = (bf16_t*)(ws + 8388608);    //  8 MiB  [1024][4096]
    bf16_t* x_bf  = (bf16_t*)(ws + 16777216);   // 16 MiB  [8192][1024]
    bf16_t* h_bf  = (bf16_t*)(ws + 33554432);   // 64 MiB  [8192][4096]
    // FFT scratch nested inside the h_bf window (all FFT work precedes GEMM1):
    float2* spec  = (float2*)(ws + 33554432);   // 32 MiB ..48 MiB+8
    float2* fftA  = (float2*)(ws + 51380224);   // 49 MiB ..65 MiB
    float2* fftB  = (float2*)(ws + 69206016);   // 66 MiB ..82 MiB
    bf16_t* w_nat = (bf16_t*)(ws + 87031808);   // 83 MiB ..91 MiB (bf16 packed)

    auto run_decompress = [&](const float* cr, const float* ci, const int* idx,
                              const float* scale, bf16_t* wT, int R, int C) {
        zero2_kernel<<<(M_HALF + 1 + 255)/256, 256, 0, stream>>>(spec, M_HALF + 1);
        scatter_kernel<<<(keep + 255)/256, 256, 0, stream>>>(cr, ci, idx, spec, keep);
        // radices: 512 (prep fused, in-block 8^3), 64, 64 (bf16 out) -> 2^21
        ifft_pass512_first<<<4096/8, 512, 0, stream>>>(spec, fftA, scale);
        ifft_pass64<512>   <<<M64/32, 256, 0, stream>>>(fftA, fftB);
        ifft_pass64_bf<32768><<<M64/32, 256, 0, stream>>>(fftB, w_nat);
        dim3 tg(C/32, R/32);
        transpose_bf_kernel<<<tg, 256, 0, stream>>>(w_nat, wT, R, C);
    };

    run_decompress(fc_cr, fc_ci, fc_idx, fc_scale, w_fcT, 1024, 4096);
    run_decompress(pj_cr, pj_ci, pj_idx, pj_scale, w_pjT, 4096, 1024);

    cvt_bf16_kernel<<<8388608/4/256, 256, 0, stream>>>(x, x_bf, 8388608/4);

    // GEMM1: 128x256 tiles, grid = (4096/256) x (8192/128) = 16 x 64 = 1024
    //        XCD chunks: CR=16 ty x CC=8 tx (GXC = 16/8 = 2); per-XCD A 4MB+B 4MB
    gemm_bt8w<0><<<dim3(4096/256, 8192/128), 512, 0, stream>>>(
        x_bf, w_fcT, fc_bias, h_bf, 8192, 4096, 1024, 16, 8, 2);

    // GEMM2: 128x128 tiles, grid = 8 x 64 = 512; XCD chunks 8x8 (GXC = 1)
    gemm_bt8<1><<<dim3(1024/128, 8192/128), 512, 0, stream>>>(
        h_bf, w_pjT, pj_bias, d_out, 8192, 1024, 4096, 8, 8, 1);

    (void)n_in; (void)out_size; (void)ws_size;
}